// Round 1
// baseline (375.652 us; speedup 1.0000x reference)
//
#include <hip/hip_runtime.h>

typedef __bf16 bf16;
typedef __bf16 bf16x8 __attribute__((ext_vector_type(8)));
typedef __bf16 bf16x4 __attribute__((ext_vector_type(4)));
typedef float  f32x4  __attribute__((ext_vector_type(4)));

#define BATCH 65536
#define NIN   128
#define HDIM  512
#define NCAT  608   // 599 spline logits + a + b, padded to 608 (38 x 16)

// ---------------------------------------------------------------------------
// Kernel 0: cast weights to bf16; assemble Wcat[608][512] = [WV; Wa; Wb; 0-pad]
// ---------------------------------------------------------------------------
__global__ __launch_bounds__(256) void prep_kernel(
    const float* W1, const float* W2, const float* WV,
    const float* bV, const float* Wa, const float* ba,
    const float* Wb, const float* bb,
    bf16* w1b, bf16* w2b, bf16* wcat, float* bcat)
{
    int idx = blockIdx.x * 256 + threadIdx.x;
    const int n1 = 512 * 128, n2 = 512 * 512, n3 = NCAT * 512;
    if (idx < n1) { w1b[idx] = (bf16)W1[idx]; return; }
    idx -= n1;
    if (idx < n2) { w2b[idx] = (bf16)W2[idx]; return; }
    idx -= n2;
    if (idx < n3) {
        int n = idx >> 9, k = idx & 511;
        float v = 0.f;
        if (n < 599)       v = WV[n * 512 + k];
        else if (n == 599) v = Wa[k];
        else if (n == 600) v = Wb[k];
        wcat[idx] = (bf16)v;
        return;
    }
    idx -= n3;
    if (idx < NCAT) {
        float v = 0.f;
        if (idx < 599)       v = bV[idx];
        else if (idx == 599) v = ba[0];
        else if (idx == 600) v = bb[0];
        bcat[idx] = v;
    }
}

// ---------------------------------------------------------------------------
// Kernels 1&2: C[64 x 512] = A[64 x K] @ W[512 x K]^T + bias -> LN -> ReLU -> bf16
// 8 waves as 2(M) x 4(N); wave tile 32 x 128; 16 MFMA (16x16x32 bf16) / K-step.
// LDS rows padded to 40 elems (80 B) -> conflict-free ds_read_b128 frags.
// ---------------------------------------------------------------------------
template <int KDIM, bool AF32>
__global__ __launch_bounds__(512) void gemm_ln_relu(
    const void* Av, const bf16* __restrict__ W,
    const float* __restrict__ bias, const float* __restrict__ gamma,
    const float* __restrict__ beta, bf16* out)
{
    __shared__ bf16 As[64][40];
    __shared__ bf16 Bs[512][40];
    __shared__ float Psum[64][4];
    __shared__ float Psq[64][4];

    const int t    = threadIdx.x;
    const int lane = t & 63, wid = t >> 6;
    const int wm = wid >> 2, wn = wid & 3;          // 2 x 4 wave grid
    const int l16 = lane & 15, g16 = lane >> 4;
    const long row0 = (long)blockIdx.x * 64;

    f32x4 acc[2][8];
    const f32x4 zero4 = {0.f, 0.f, 0.f, 0.f};
#pragma unroll
    for (int a = 0; a < 2; ++a)
#pragma unroll
        for (int b = 0; b < 8; ++b) acc[a][b] = zero4;

    const int ar = t >> 3, ac = (t & 7) * 4;        // A staging: 4 elems/thread

    for (int k0 = 0; k0 < KDIM; k0 += 32) {
        __syncthreads();
        // --- stage A tile (64 x 32) ---
        if (AF32) {
            const float* A = (const float*)Av;
            float4 v = *(const float4*)&A[(row0 + ar) * KDIM + k0 + ac];
            bf16x4 h; h[0] = (bf16)v.x; h[1] = (bf16)v.y; h[2] = (bf16)v.z; h[3] = (bf16)v.w;
            *(bf16x4*)&As[ar][ac] = h;
        } else {
            const bf16* A = (const bf16*)Av;
            *(bf16x4*)&As[ar][ac] = *(const bf16x4*)&A[(row0 + ar) * KDIM + k0 + ac];
        }
        // --- stage B tile (512 x 32): thread t stages W row t ---
        {
            const bf16* wr = &W[(long)t * KDIM + k0];
            *(bf16x8*)&Bs[t][0]  = *(const bf16x8*)&wr[0];
            *(bf16x8*)&Bs[t][8]  = *(const bf16x8*)&wr[8];
            *(bf16x8*)&Bs[t][16] = *(const bf16x8*)&wr[16];
            *(bf16x8*)&Bs[t][24] = *(const bf16x8*)&wr[24];
        }
        __syncthreads();
        // --- compute ---
        bf16x8 af[2];
#pragma unroll
        for (int fm = 0; fm < 2; ++fm)
            af[fm] = *(const bf16x8*)&As[wm * 32 + fm * 16 + l16][g16 * 8];
#pragma unroll
        for (int fn = 0; fn < 8; ++fn) {
            bf16x8 bfv = *(const bf16x8*)&Bs[wn * 128 + fn * 16 + l16][g16 * 8];
#pragma unroll
            for (int fm = 0; fm < 2; ++fm)
                acc[fm][fn] = __builtin_amdgcn_mfma_f32_16x16x32_bf16(af[fm], bfv, acc[fm][fn], 0, 0, 0);
        }
    }

    // --- epilogue: + bias, LayerNorm (per row over 512), ReLU, bf16 store ---
#pragma unroll
    for (int fm = 0; fm < 2; ++fm)
#pragma unroll
        for (int fn = 0; fn < 8; ++fn) {
            float bv = bias[wn * 128 + fn * 16 + l16];
#pragma unroll
            for (int i = 0; i < 4; ++i) acc[fm][fn][i] += bv;
        }
    // partial row stats over this wave's 128 cols (reduce across l16 group)
#pragma unroll
    for (int fm = 0; fm < 2; ++fm)
#pragma unroll
        for (int i = 0; i < 4; ++i) {
            float s = 0.f, q = 0.f;
#pragma unroll
            for (int fn = 0; fn < 8; ++fn) { float v = acc[fm][fn][i]; s += v; q += v * v; }
#pragma unroll
            for (int m = 1; m < 16; m <<= 1) { s += __shfl_xor(s, m); q += __shfl_xor(q, m); }
            if (l16 == 0) {
                int lr = wm * 32 + fm * 16 + g16 * 4 + i;
                Psum[lr][wn] = s; Psq[lr][wn] = q;
            }
        }
    __syncthreads();
#pragma unroll
    for (int fm = 0; fm < 2; ++fm)
#pragma unroll
        for (int i = 0; i < 4; ++i) {
            int lr = wm * 32 + fm * 16 + g16 * 4 + i;
            float s = Psum[lr][0] + Psum[lr][1] + Psum[lr][2] + Psum[lr][3];
            float q = Psq[lr][0] + Psq[lr][1] + Psq[lr][2] + Psq[lr][3];
            float mean = s * (1.f / 512.f);
            float var  = q * (1.f / 512.f) - mean * mean;
            float rstd = rsqrtf(var + 1e-5f);
            long grow = row0 + lr;
#pragma unroll
            for (int fn = 0; fn < 8; ++fn) {
                int col = wn * 128 + fn * 16 + l16;
                float o = (acc[fm][fn][i] - mean) * rstd * gamma[col] + beta[col];
                o = fmaxf(o, 0.f);
                out[grow * 512 + col] = (bf16)o;
            }
        }
}

// ---------------------------------------------------------------------------
// Kernel 3: sp[64 x 608] = x[64 x 512] @ Wcat[608 x 512]^T + bcat
// 8 waves as 4(M) x 2(N); wave tile 16 x 304 (19 N-frags).
// cols 0..598 -> sp (bf16); col 599 -> a (f32); col 600 -> b (f32).
// ---------------------------------------------------------------------------
__global__ __launch_bounds__(512) void gemm_sp(
    const bf16* __restrict__ A, const bf16* __restrict__ W,
    const float* __restrict__ bcat, bf16* __restrict__ sp, float* __restrict__ ab)
{
    __shared__ bf16 As[64][40];
    __shared__ bf16 Bs[NCAT][40];

    const int t    = threadIdx.x;
    const int lane = t & 63, wid = t >> 6;
    const int wm = wid >> 1, wn = wid & 1;          // 4 x 2 wave grid
    const int l16 = lane & 15, g16 = lane >> 4;
    const long row0 = (long)blockIdx.x * 64;

    f32x4 acc[19];
    const f32x4 zero4 = {0.f, 0.f, 0.f, 0.f};
#pragma unroll
    for (int i = 0; i < 19; ++i) acc[i] = zero4;

    const int ar = t >> 3, ac = (t & 7) * 4;

    for (int k0 = 0; k0 < 512; k0 += 32) {
        __syncthreads();
        *(bf16x4*)&As[ar][ac] = *(const bf16x4*)&A[(row0 + ar) * 512 + k0 + ac];
        for (int r = t; r < NCAT; r += 512) {
            const bf16* wr = &W[(long)r * 512 + k0];
            *(bf16x8*)&Bs[r][0]  = *(const bf16x8*)&wr[0];
            *(bf16x8*)&Bs[r][8]  = *(const bf16x8*)&wr[8];
            *(bf16x8*)&Bs[r][16] = *(const bf16x8*)&wr[16];
            *(bf16x8*)&Bs[r][24] = *(const bf16x8*)&wr[24];
        }
        __syncthreads();
        bf16x8 af = *(const bf16x8*)&As[wm * 16 + l16][g16 * 8];
#pragma unroll
        for (int fn = 0; fn < 19; ++fn) {
            bf16x8 bfv = *(const bf16x8*)&Bs[wn * 304 + fn * 16 + l16][g16 * 8];
            acc[fn] = __builtin_amdgcn_mfma_f32_16x16x32_bf16(af, bfv, acc[fn], 0, 0, 0);
        }
    }

#pragma unroll
    for (int fn = 0; fn < 19; ++fn) {
        int col = wn * 304 + fn * 16 + l16;
        float bv = bcat[col];
#pragma unroll
        for (int i = 0; i < 4; ++i) {
            long grow = row0 + wm * 16 + g16 * 4 + i;
            float v = acc[fn][i] + bv;
            if (col < 599)       sp[grow * NCAT + col] = (bf16)v;
            else if (col == 599) ab[grow * 2 + 0] = v;
            else if (col == 600) ab[grow * 2 + 1] = v;
        }
    }
}

// ---------------------------------------------------------------------------
// Kernel 4: per-row spline. One wave per row (4 rows / 256-thread block).
// Wave-parallel softmax + shfl-scan cumsum; cw/ch/D staged in LDS; per-output
// binary search (upper_bound) + rational-quadratic formula. All f32.
// ---------------------------------------------------------------------------
__global__ __launch_bounds__(256) void spline_epilogue(
    const bf16* __restrict__ sp, const float* __restrict__ ab, float* __restrict__ out)
{
    __shared__ float cwS[4][208];
    __shared__ float chS[4][208];
    __shared__ float dS[4][208];

    const int t = threadIdx.x;
    const int lane = t & 63, wid = t >> 6;
    const long row = (long)blockIdx.x * 4 + wid;
    float* cw = cwS[wid];
    float* ch = chS[wid];
    float* dd = dS[wid];
    const bf16* spr = sp + row * NCAT;
    const bool act = lane < 50;

    const float sa = __expf(ab[row * 2 + 0]);   // scale_a = exp(x @ Wa + ba)
    const float sb = ab[row * 2 + 1];           // scale_b

    // ---- softmax(Wp) -> Wp = 0.001 + 0.8*softmax -> cumsum -> cw[0..200] ----
    {
        float x[4];
#pragma unroll
        for (int j = 0; j < 4; ++j) x[j] = act ? (float)spr[4 * lane + j] : -1e30f;
        float m = fmaxf(fmaxf(x[0], x[1]), fmaxf(x[2], x[3]));
        for (int d = 1; d < 64; d <<= 1) m = fmaxf(m, __shfl_xor(m, d));
        float e[4], ls = 0.f;
#pragma unroll
        for (int j = 0; j < 4; ++j) { e[j] = act ? __expf(x[j] - m) : 0.f; ls += e[j]; }
        float s = ls;
        for (int d = 1; d < 64; d <<= 1) s += __shfl_xor(s, d);
        float inv = 1.f / s;
        float c[4], run = 0.f;
#pragma unroll
        for (int j = 0; j < 4; ++j) { float p = act ? (0.001f + 0.8f * e[j] * inv) : 0.f; run += p; c[j] = run; }
        float ts = run;
        for (int d = 1; d < 64; d <<= 1) { float u = __shfl_up(ts, d); if (lane >= d) ts += u; }
        float excl = ts - run;
        if (act) {
#pragma unroll
            for (int j = 0; j < 4; ++j) cw[4 * lane + 1 + j] = excl + c[j];
        }
        if (lane == 0) cw[0] = 0.f;
        if (lane == 0) cw[200] = 1.0f;   // cw[:, -1].set(1.0) — after lane49's write
    }

    // ---- softmax(Hp) -> cumsum -> ch = sa * [0, cumsum] + sb ----
    {
        float x[4];
#pragma unroll
        for (int j = 0; j < 4; ++j) x[j] = act ? (float)spr[200 + 4 * lane + j] : -1e30f;
        float m = fmaxf(fmaxf(x[0], x[1]), fmaxf(x[2], x[3]));
        for (int d = 1; d < 64; d <<= 1) m = fmaxf(m, __shfl_xor(m, d));
        float e[4], ls = 0.f;
#pragma unroll
        for (int j = 0; j < 4; ++j) { e[j] = act ? __expf(x[j] - m) : 0.f; ls += e[j]; }
        float s = ls;
        for (int d = 1; d < 64; d <<= 1) s += __shfl_xor(s, d);
        float inv = 1.f / s;
        float c[4], run = 0.f;
#pragma unroll
        for (int j = 0; j < 4; ++j) { float p = act ? (0.001f + 0.8f * e[j] * inv) : 0.f; run += p; c[j] = run; }
        float ts = run;
        for (int d = 1; d < 64; d <<= 1) { float u = __shfl_up(ts, d); if (lane >= d) ts += u; }
        float excl = ts - run;
        if (act) {
#pragma unroll
            for (int j = 0; j < 4; ++j) ch[4 * lane + 1 + j] = fmaf(sa, excl + c[j], sb);
        }
        if (lane == 0) ch[0] = sb;
    }

    // ---- D = [EDGE, 0.001 + softplus(Dp[0..198]), EDGE] ----
    {
        const float EC = logf(expf(0.999f) - 1.0f);   // EDGE_CONST
        if (act) {
#pragma unroll
            for (int j = 0; j < 4; ++j) {
                int ti = 4 * lane + j;
                if (ti < 199) {
                    float x = (float)spr[400 + ti];
                    float spl = fmaxf(x, 0.f) + log1pf(__expf(-fabsf(x)));
                    dd[1 + ti] = 0.001f + spl;
                }
            }
        }
        if (lane == 0) { dd[0] = EC; dd[200] = EC; }
    }

    __syncthreads();

    // ---- per-output: searchsorted(cw, tau, right)-1 then RQ spline ----
    if (act) {
        float o[4];
#pragma unroll
        for (int j = 0; j < 4; ++j) {
            int jj = 4 * lane + j;
            float tau = ((float)jj + 0.5f) / 200.0f;
            int lo = 0, hi = 201;                        // upper_bound on cw
            while (lo < hi) { int mid = (lo + hi) >> 1; if (cw[mid] <= tau) lo = mid + 1; else hi = mid; }
            int b = lo - 1;
            float cwb = cw[b], w = cw[b + 1] - cwb;
            float chb = ch[b], h = ch[b + 1] - chb;
            float d0 = dd[b], d1 = dd[b + 1];
            float delta = h / w;
            float th = (tau - cwb) / w;
            float t1 = th * (1.f - th);
            float numer = h * (delta * th * th + d0 * t1);
            float denom = delta + (d0 + d1 - 2.f * delta) * t1;
            o[j] = chb + numer / denom;
        }
        float4 ov = make_float4(o[0], o[1], o[2], o[3]);
        *(float4*)&out[row * 200 + 4 * lane] = ov;
    }
}

// ---------------------------------------------------------------------------
// Host launcher
// ---------------------------------------------------------------------------
extern "C" void kernel_launch(void* const* d_in, const int* in_sizes, int n_in,
                              void* d_out, int out_size, void* d_ws, size_t ws_size,
                              hipStream_t stream)
{
    const float* inputs = (const float*)d_in[0];
    const float* W1  = (const float*)d_in[1];
    const float* b1  = (const float*)d_in[2];
    const float* g1  = (const float*)d_in[3];
    const float* be1 = (const float*)d_in[4];
    const float* W2  = (const float*)d_in[5];
    const float* b2  = (const float*)d_in[6];
    const float* g2  = (const float*)d_in[7];
    const float* be2 = (const float*)d_in[8];
    const float* WV  = (const float*)d_in[9];
    const float* bV  = (const float*)d_in[10];
    const float* Wa  = (const float*)d_in[11];
    const float* ba  = (const float*)d_in[12];
    const float* Wb  = (const float*)d_in[13];
    const float* bb  = (const float*)d_in[14];
    float* out = (float*)d_out;

    // workspace layout (bytes), all offsets 256-aligned
    char* ws = (char*)d_ws;
    bf16*  w1b  = (bf16*) (ws + 0);          //   131072
    bf16*  w2b  = (bf16*) (ws + 131072);     //   524288
    bf16*  wcat = (bf16*) (ws + 655360);     //   622592
    float* bcat = (float*)(ws + 1277952);    //     4096 (608 used)
    bf16*  xbuf = (bf16*) (ws + 1282048);    // 67108864 (B x 512, in-place L1->L2)
    bf16*  spb  = (bf16*) (ws + 68390912);   // 79691776 (B x 608)
    float* ab   = (float*)(ws + 148082688);  //   524288 (B x 2)

    const int preptot = 512 * 128 + 512 * 512 + NCAT * 512 + NCAT;
    prep_kernel<<<(preptot + 255) / 256, 256, 0, stream>>>(
        W1, W2, WV, bV, Wa, ba, Wb, bb, w1b, w2b, wcat, bcat);

    gemm_ln_relu<128, true ><<<BATCH / 64, 512, 0, stream>>>(inputs, w1b, b1, g1, be1, xbuf);
    gemm_ln_relu<512, false><<<BATCH / 64, 512, 0, stream>>>(xbuf,   w2b, b2, g2, be2, xbuf);
    gemm_sp<<<BATCH / 64, 512, 0, stream>>>(xbuf, wcat, bcat, spb, ab);
    spline_epilogue<<<BATCH / 4, 256, 0, stream>>>(spb, ab, out);
}